// Round 2
// baseline (849.396 us; speedup 1.0000x reference)
//
#include <hip/hip_runtime.h>
#include <cstdint>
#include <cstddef>

#define N_NODES 100000
#define N_EDGES 1600000
#define HD 128
#define OUTC 64
#define WDIM 512
#define RANKK 10
#define SLOPE 0.01f

static __device__ __forceinline__ float lrelu(float v){ return v >= 0.f ? v : SLOPE*v; }

// ---------------- styles: st0[2560] = w[0]@aff0 + b0 ; st1[1920] = w[1]@aff1 + b1 ----
__global__ void k_styles(const float* __restrict__ w,
                         const float* __restrict__ a0w, const float* __restrict__ a0b,
                         const float* __restrict__ a1w, const float* __restrict__ a1b,
                         float* __restrict__ st0, float* __restrict__ st1){
  int j = blockIdx.x*blockDim.x + threadIdx.x;
  if (j < 2560){
    float s = a0b[j];
    for (int k=0;k<WDIM;k++) s += w[k]*a0w[k*2560 + j];
    st0[j] = s;
  } else if (j < 2560+1920){
    int jj = j - 2560;
    float s = a1b[jj];
    for (int k=0;k<WDIM;k++) s += w[WDIM + k]*a1w[k*1920 + jj];
    st1[jj] = s;
  }
}

// ---------------- modulated + row-normalized weight, stored TRANSPOSED: wt[i][o] ----
__global__ void k_wmod(const float* __restrict__ st, const float* __restrict__ wgt,
                       float* __restrict__ wt, int c_out){
  int o = blockIdx.x, i = threadIdx.x;   // 128 threads = 2 waves
  float mod = 0.f;
  #pragma unroll
  for (int r=0;r<RANKK;r++) mod += st[o*RANKK + r] * st[c_out*RANKK + r*HD + i];
  mod *= 0.31622776601683794f;           // 1/sqrt(RANK)
  float wv = wgt[o*HD + i] * (mod + 1.f);
  float sq = wv*wv;
  #pragma unroll
  for (int d=1; d<64; d<<=1) sq += __shfl_xor(sq, d, 64);
  __shared__ float red[2];
  if ((i & 63) == 0) red[i>>6] = sq;
  __syncthreads();
  float norm = sqrtf(red[0] + red[1]) + 1e-8f;
  wt[i*c_out + o] = wv / norm;
}

// ---------------- M2 = node_w @ (I + cat2) ; biasv = cat1_b + cat2_b + node_b@(I+cat2)
__global__ void k_m2bias(const float* __restrict__ node_w, const float* __restrict__ node_b,
                         const float* __restrict__ cat2_w, const float* __restrict__ cat1_b,
                         const float* __restrict__ cat2_b,
                         float* __restrict__ M2, float* __restrict__ biasv){
  int i = threadIdx.x;
  int k = blockIdx.x;
  if (k < HD){
    float s = node_w[k*HD + i];
    for (int j=0;j<HD;j++) s += node_w[k*HD + j]*cat2_w[j*HD + i];
    M2[k*HD + i] = s;
  } else {
    float s = cat1_b[i] + cat2_b[i] + node_b[i];
    for (int j=0;j<HD;j++) s += node_b[j]*cat2_w[j*HD + i];
    biasv[i] = s;
  }
}

// ---------------- CSR build ----------------
__global__ void k_hist(const int* __restrict__ ei, int* __restrict__ cnt){
  int e = blockIdx.x*blockDim.x + threadIdx.x;
  if (e < N_EDGES) atomicAdd(&cnt[ei[N_EDGES + e]], 1);
}

__global__ __launch_bounds__(1024) void k_scan(const int* __restrict__ cnt,
                                               int* __restrict__ rowptr, int* __restrict__ cursor){
  __shared__ int part[1024];
  int tid = threadIdx.x;
  const int chunk = (N_NODES + 1023)/1024;
  int lo = tid*chunk;
  int hi = min(lo + chunk, N_NODES);
  int s = 0;
  for (int i=lo;i<hi;i++) s += cnt[i];
  part[tid] = s;
  __syncthreads();
  for (int off=1; off<1024; off<<=1){
    int t = (tid >= off) ? part[tid-off] : 0;
    __syncthreads();
    part[tid] += t;
    __syncthreads();
  }
  int run = part[tid] - s;               // exclusive prefix of this chunk
  for (int i=lo;i<hi;i++){
    rowptr[i] = run; cursor[i] = run; run += cnt[i];
  }
  if (tid == 1023) rowptr[N_NODES] = part[1023];
}

__global__ void k_fill(const int* __restrict__ ei, const float* __restrict__ ew,
                       int* __restrict__ cursor, int* __restrict__ ssrc, float* __restrict__ sortw){
  int e = blockIdx.x*blockDim.x + threadIdx.x;
  if (e < N_EDGES){
    int d = ei[N_EDGES + e];
    int pos = atomicAdd(&cursor[d], 1);
    ssrc[pos] = ei[e];
    sortw[pos] = ew[e];
  }
}

// ---------------- gather-accumulate: one node per 64-lane wave, float2 per lane ----
__global__ void k_gather(const int* __restrict__ rowptr, const int* __restrict__ ssrc,
                         const float* __restrict__ sortw, const float* __restrict__ elw,
                         const float* __restrict__ elb, float* __restrict__ accb){
  int wid = (blockIdx.x * blockDim.x + threadIdx.x) >> 6;
  int lane = threadIdx.x & 63;
  if (wid >= N_NODES) return;
  int beg = rowptr[wid], end = rowptr[wid+1];
  float sx = 0.f, sy = 0.f;
  for (int e = beg; e < end; e++){
    int src = ssrc[e];
    float wv = sortw[e];
    float2 t = *(const float2*)&elw[(size_t)src*HD + lane*2];
    sx += t.x*wv; sy += t.y*wv;
  }
  float2 o = make_float2(sx + elb[lane*2], sy + elb[lane*2+1]);
  *(float2*)&accb[(size_t)wid*HD + lane*2] = o;
}

// ---------------- fused node chain: out = L(L(L(acc@M1 + x@M2 + bv) @ W0T + b0) @ W1T + b1)
// 128-row tile / block, 512 threads. A held k-major in sA with XOR swizzle r^(2*(k&15)).
__global__ __launch_bounds__(512, 2) void k_fused(
    const float* __restrict__ accb, const float* __restrict__ x,
    const float* __restrict__ cat1_w, const float* __restrict__ M2,
    const float* __restrict__ biasv, const float* __restrict__ W0T,
    const float* __restrict__ W1T, const float* __restrict__ sb0,
    const float* __restrict__ sb1, float* __restrict__ outp){
  __shared__ float sA[HD*HD];
  __shared__ float sB[HD*HD];
  const int tid = threadIdx.x;
  const int cg = tid & 15;        // col group: cols 2cg+{0,1}+32j
  const int rg = tid >> 4;        // row group: rows 2rg+{0,1}+64m
  const int row0 = blockIdx.x * HD;

  auto stage_a = [&](const float* __restrict__ src){
    #pragma unroll
    for (int p=0;p<8;p++){
      int o = (tid + p*512)*4;
      int r = o >> 7, k = o & 127;
      float4 v = make_float4(0.f,0.f,0.f,0.f);
      if (row0 + r < N_NODES) v = *(const float4*)&src[(size_t)(row0+r)*HD + k];
      sA[(k+0)*HD + (r ^ (2*((k+0)&15)))] = v.x;
      sA[(k+1)*HD + (r ^ (2*((k+1)&15)))] = v.y;
      sA[(k+2)*HD + (r ^ (2*((k+2)&15)))] = v.z;
      sA[(k+3)*HD + (r ^ (2*((k+3)&15)))] = v.w;
    }
  };
  auto stage_b = [&](const float* __restrict__ src){
    #pragma unroll
    for (int p=0;p<8;p++){
      int o = (tid + p*512)*4;
      *(float4*)&sB[o] = *(const float4*)&src[o];
    }
  };
  auto gemm = [&](float (&v)[4][8]){
    #pragma unroll 4
    for (int k=0;k<HD;k++){
      int s = 2*(k & 15);
      float2 a0 = *(const float2*)&sA[k*HD + ((2*rg) ^ s)];
      float2 a1 = *(const float2*)&sA[k*HD + (((2*rg) ^ s) + 64)];
      float2 b0 = *(const float2*)&sB[k*HD + 2*cg];
      float2 b1 = *(const float2*)&sB[k*HD + 2*cg + 32];
      float2 b2 = *(const float2*)&sB[k*HD + 2*cg + 64];
      float2 b3 = *(const float2*)&sB[k*HD + 2*cg + 96];
      float av[4] = {a0.x, a0.y, a1.x, a1.y};
      float bv[8] = {b0.x,b0.y,b1.x,b1.y,b2.x,b2.y,b3.x,b3.y};
      #pragma unroll
      for (int rr=0;rr<4;rr++)
        #pragma unroll
        for (int cc=0;cc<8;cc++)
          v[rr][cc] += av[rr]*bv[cc];
    }
  };
  auto writeT = [&](float (&v)[4][8]){   // store v (rows x cols) k-major into sA
    #pragma unroll
    for (int j=0;j<4;j++)
      #pragma unroll
      for (int d=0;d<2;d++){
        int c = 2*cg + d + 32*j;
        int s = 2*(c & 15);
        #pragma unroll
        for (int m=0;m<2;m++){
          float2 t = make_float2(v[2*m][2*j+d], v[2*m+1][2*j+d]);
          *(float2*)&sA[c*HD + (((2*rg) ^ s) + 64*m)] = t;
        }
      }
  };

  float v[4][8];
  #pragma unroll
  for (int a=0;a<4;a++)
    #pragma unroll
    for (int b=0;b<8;b++) v[a][b] = 0.f;

  // phase 1: acc @ (I + cat1)
  stage_a(accb);
  stage_b(cat1_w);
  __syncthreads();
  if (tid < HD) sB[tid*HD + tid] += 1.f;   // identity
  __syncthreads();
  gemm(v);
  __syncthreads();
  // phase 2: + x @ M2, + biasv, leaky
  stage_a(x);
  stage_b(M2);
  __syncthreads();
  gemm(v);
  #pragma unroll
  for (int j=0;j<4;j++)
    #pragma unroll
    for (int d=0;d<2;d++){
      float bb = biasv[2*cg + d + 32*j];
      #pragma unroll
      for (int rr=0;rr<4;rr++) v[rr][2*j+d] = lrelu(v[rr][2*j+d] + bb);
    }
  __syncthreads();
  // phase 3: out2 @ W0T, + b0, leaky
  writeT(v);
  stage_b(W0T);
  __syncthreads();
  float h[4][8];
  #pragma unroll
  for (int a=0;a<4;a++)
    #pragma unroll
    for (int b=0;b<8;b++) h[a][b] = 0.f;
  gemm(h);
  #pragma unroll
  for (int j=0;j<4;j++)
    #pragma unroll
    for (int d=0;d<2;d++){
      float bb = sb0[2*cg + d + 32*j];
      #pragma unroll
      for (int rr=0;rr<4;rr++) h[rr][2*j+d] = lrelu(h[rr][2*j+d] + bb);
    }
  __syncthreads();
  // phase 4: h1 @ W1T (64 cols), + b1, leaky
  writeT(h);
  #pragma unroll
  for (int p=0;p<4;p++){
    int o = (tid + p*512)*4;
    int k = o >> 6, c = o & 63;
    *(float4*)&sB[k*HD + c] = *(const float4*)&W1T[o];
  }
  __syncthreads();
  float y[4][4];
  #pragma unroll
  for (int a=0;a<4;a++)
    #pragma unroll
    for (int b=0;b<4;b++) y[a][b] = 0.f;
  #pragma unroll 4
  for (int k=0;k<HD;k++){
    int s = 2*(k & 15);
    float2 a0 = *(const float2*)&sA[k*HD + ((2*rg) ^ s)];
    float2 a1 = *(const float2*)&sA[k*HD + (((2*rg) ^ s) + 64)];
    float2 b0 = *(const float2*)&sB[k*HD + 2*cg];
    float2 b1 = *(const float2*)&sB[k*HD + 2*cg + 32];
    float av[4] = {a0.x, a0.y, a1.x, a1.y};
    float bv[4] = {b0.x, b0.y, b1.x, b1.y};
    #pragma unroll
    for (int rr=0;rr<4;rr++)
      #pragma unroll
      for (int cc=0;cc<4;cc++)
        y[rr][cc] += av[rr]*bv[cc];
  }
  #pragma unroll
  for (int j=0;j<2;j++)
    #pragma unroll
    for (int d=0;d<2;d++){
      float bb = sb1[2*cg + d + 32*j];
      #pragma unroll
      for (int rr=0;rr<4;rr++) y[rr][2*j+d] = lrelu(y[rr][2*j+d] + bb);
    }
  __syncthreads();
  // bounce y through sA (as [128][64]) for coalesced float4 stores
  #pragma unroll
  for (int m=0;m<2;m++)
    #pragma unroll
    for (int e=0;e<2;e++)
      #pragma unroll
      for (int j=0;j<2;j++){
        int r = 2*rg + e + 64*m;
        int c = 2*cg + 32*j;
        *(float2*)&sA[r*OUTC + c] = make_float2(y[2*m+e][2*j], y[2*m+e][2*j+1]);
      }
  __syncthreads();
  #pragma unroll
  for (int p=0;p<4;p++){
    int o = (tid + p*512)*4;
    int r = o >> 6;
    if (row0 + r < N_NODES)
      *(float4*)&outp[(size_t)(row0+r)*OUTC + (o & 63)] = *(const float4*)&sA[o];
  }
}

extern "C" void kernel_launch(void* const* d_in, const int* in_sizes, int n_in,
                              void* d_out, int out_size, void* d_ws, size_t ws_size,
                              hipStream_t stream){
  const float* x      = (const float*)d_in[0];
  const int*   ei     = (const int*)d_in[1];
  const float* ew     = (const float*)d_in[2];
  const float* w      = (const float*)d_in[3];
  const float* elw    = (const float*)d_in[4];
  const float* elb    = (const float*)d_in[5];
  const float* node_w = (const float*)d_in[6];
  const float* node_b = (const float*)d_in[7];
  const float* cat1_w = (const float*)d_in[8];
  const float* cat1_b = (const float*)d_in[9];
  const float* cat2_w = (const float*)d_in[10];
  const float* cat2_b = (const float*)d_in[11];
  const float* a0w    = (const float*)d_in[12];
  const float* a0b    = (const float*)d_in[13];
  const float* syn0_w = (const float*)d_in[14];
  const float* syn0_b = (const float*)d_in[15];
  const float* a1w    = (const float*)d_in[16];
  const float* a1b    = (const float*)d_in[17];
  const float* syn1_w = (const float*)d_in[18];
  const float* syn1_b = (const float*)d_in[19];
  float* outp = (float*)d_out;

  float* ws     = (float*)d_ws;
  float* accb   = ws;                                   // N*128 f32
  float* st0    = ws + (size_t)N_NODES*HD;              // 2560
  float* st1    = st0 + 2560;                           // 1920
  float* M2     = st1 + 1920;                           // 128*128
  float* biasv  = M2 + HD*HD;                           // 128
  float* W0T    = biasv + HD;                           // 128*128
  float* W1T    = W0T + HD*HD;                          // 128*64
  int*   cnt    = (int*)(W1T + HD*OUTC);                // N
  int*   rowptr = cnt + N_NODES;                        // N+1
  int*   cursor = rowptr + N_NODES + 1;                 // N
  int*   ssrc   = cursor + N_NODES;                     // E
  float* sortw  = (float*)(ssrc + N_EDGES);             // E

  hipMemsetAsync(cnt, 0, N_NODES*sizeof(int), stream);
  k_styles<<<(2560+1920+255)/256, 256, 0, stream>>>(w, a0w, a0b, a1w, a1b, st0, st1);
  k_wmod<<<HD, HD, 0, stream>>>(st0, syn0_w, W0T, HD);
  k_wmod<<<OUTC, HD, 0, stream>>>(st1, syn1_w, W1T, OUTC);
  k_m2bias<<<HD+1, HD, 0, stream>>>(node_w, node_b, cat2_w, cat1_b, cat2_b, M2, biasv);
  k_hist<<<(N_EDGES+255)/256, 256, 0, stream>>>(ei, cnt);
  k_scan<<<1, 1024, 0, stream>>>(cnt, rowptr, cursor);
  k_fill<<<(N_EDGES+255)/256, 256, 0, stream>>>(ei, ew, cursor, ssrc, sortw);
  k_gather<<<(N_NODES*64)/256, 256, 0, stream>>>(rowptr, ssrc, sortw, elw, elb, accb);
  k_fused<<<(N_NODES+HD-1)/HD, 512, 0, stream>>>(accb, x, cat1_w, M2, biasv, W0T, W1T,
                                                 syn0_b, syn1_b, outp);
}